// Round 4
// baseline (265.505 us; speedup 1.0000x reference)
//
#include <hip/hip_runtime.h>

#define NN   32768
#define HD   128
#define EE   524288
#define GG   256
#define EPG  2048
#define CCd  16
#define LLd  3

typedef short short8 __attribute__((ext_vector_type(8)));   // 8 bf16 = 4 VGPRs
typedef float f32x4 __attribute__((ext_vector_type(4)));

__device__ __forceinline__ unsigned short f2bf(float f) {
  unsigned u = __builtin_bit_cast(unsigned, f);
  return (unsigned short)((u + 0x7FFFu + ((u >> 16) & 1u)) >> 16);  // RNE
}
__device__ __forceinline__ unsigned bfpack(float a, float b) {
  return (unsigned)f2bf(a) | ((unsigned)f2bf(b) << 16);
}

// hTs layout: [f][t] bf16, stride 128 (no pad), 16-B chunks XOR-swizzled so that
// row-major b128 reads (lanes vary f low bits) AND column writes (lanes vary f
// high bits) both spread across bank groups:  phys = (c&8) | ((c ^ f ^ (f>>3)) & 7)
__device__ __forceinline__ int hchunk(int f, int c) {   // c = t>>3 in [0,16)
  return f * 128 + (((c & 8) | ((c ^ f ^ (f >> 3)) & 7)) << 3);
}
__device__ __forceinline__ int hidx(int f, int t) {
  return hchunk(f, t >> 3) + (t & 7);
}

// ---------------- convert weights to bf16 + reg_loss accumulate ----------------
__global__ __launch_bounds__(256) void convert_w_kernel(const float* __restrict__ Wn, const float* __restrict__ Wo,
                                                        const float* __restrict__ Wr, const float* __restrict__ bo,
                                                        unsigned* __restrict__ Wnb, unsigned* __restrict__ Wob,
                                                        unsigned* __restrict__ Wrb, float* __restrict__ wsreg) {
  int i = blockIdx.x * 256 + threadIdx.x;   // 48 blocks; 4 floats per array per thread
  float4 a = *(const float4*)(Wn + (size_t)i * 4);
  float4 b = *(const float4*)(Wo + (size_t)i * 4);
  float4 c = *(const float4*)(Wr + (size_t)i * 4);
  *(uint2*)(Wnb + (size_t)i * 2) = make_uint2(bfpack(a.x, a.y), bfpack(a.z, a.w));
  *(uint2*)(Wob + (size_t)i * 2) = make_uint2(bfpack(b.x, b.y), bfpack(b.z, b.w));
  *(uint2*)(Wrb + (size_t)i * 2) = make_uint2(bfpack(c.x, c.y), bfpack(c.z, c.w));
  float s = fabsf(b.x) + fabsf(b.y) + fabsf(b.z) + fabsf(b.w);
  if (blockIdx.x == 0 && threadIdx.x < 96) {       // 384 bo elements
    float4 d = *(const float4*)(bo + threadIdx.x * 4);
    s += fabsf(d.x) + fabsf(d.y) + fabsf(d.z) + fabsf(d.w);
  }
#pragma unroll
  for (int mk = 1; mk < 64; mk <<= 1) s += __shfl_xor(s, mk, 64);
  if ((threadIdx.x & 63) == 0) atomicAdd(wsreg, s);
}

// ---------------- fully fused per-graph network ----------------
// grid 256 (1 block/graph), 512 threads (8 waves; wave w owns node rows [16w,16w+16)).
// Phase 0: zero Mlds; x -> hTs (coalesced reads, swizzled writes); s -> sTs; colsum.
// Phase 1: 2048 edge LDS-atomics into packed u16 counts, quad-XOR-swizzled layout.
// Phase 2: in-place count->bf16 conversion (x inv-degree); fin/fout -> small LDS.
// Layers:  M-phase MFMA (B from Mlds) -> packed single-bpermute transpose ->
//          main/Wr MFMA with W B-frags read DIRECTLY from bf16 global (L1/L2
//          broadcast; identical 64B-line addresses across all waves/blocks).
//          Only 2 barriers per layer.
__global__ __launch_bounds__(512) void fused_kernel(
    const float* __restrict__ x,
    const int* __restrict__ esrc, const int* __restrict__ etgt, const int* __restrict__ emask,
    const unsigned short* __restrict__ Wnb, const unsigned short* __restrict__ Wob,
    const unsigned short* __restrict__ Wrb,
    const float* __restrict__ bn, const float* __restrict__ bo,
    const float* __restrict__ lng, const float* __restrict__ lnb,
    const float* __restrict__ s,
    const float* __restrict__ flng, const float* __restrict__ flnb,
    const float* __restrict__ linw, const float* __restrict__ bias,
    float* __restrict__ out, float* __restrict__ l1g) {
  __shared__ __align__(16) unsigned short hTs[128 * 128];  // 32.0 KB  h^T, XOR-swizzled
  __shared__ __align__(16) unsigned short sTs[16 * 136];   //  4.3 KB  s^T [c][t]
  __shared__ __align__(16) unsigned Mlds[2 * 128 * 64];    // 64.0 KB  counts -> bf16 M; pool scratch later
  __shared__ float finS[128], foutS[128];
  __shared__ float colsumS[CCd], xcs[CCd], axcs[CCd], msk[CCd];

  const int g = blockIdx.x;
  const int tid = threadIdx.x;
  const int wave = tid >> 6;
  const int lane = tid & 63;
  const int m = lane & 15;
  const int q = lane >> 4;
  const int t0 = wave << 4;

  // ---- phase 0: zero Mlds + stage x->hTs (swizzled), s->sTs, colsum ----
  {
    uint4* cz = (uint4*)Mlds;   // 4096 uint4
#pragma unroll
    for (int i = 0; i < 8; ++i) cz[i * 512 + tid] = make_uint4(0u, 0u, 0u, 0u);

    const float4* xg = (const float4*)(x + (size_t)g * 16384);
#pragma unroll
    for (int i = 0; i < 8; ++i) {
      int flat = i * 512 + tid;           // 4096 float4s, fully coalesced
      int t = flat >> 5, f0 = (flat & 31) << 2;
      float4 v = xg[flat];
      hTs[hidx(f0 + 0, t)] = f2bf(v.x);
      hTs[hidx(f0 + 1, t)] = f2bf(v.y);
      hTs[hidx(f0 + 2, t)] = f2bf(v.z);
      hTs[hidx(f0 + 3, t)] = f2bf(v.w);
    }
    {
      int t = tid >> 2, c0 = (tid & 3) << 2;
      float4 v = *(const float4*)(s + (size_t)g * 2048 + t * 16 + c0);
      sTs[(c0 + 0) * 136 + t] = f2bf(v.x);
      sTs[(c0 + 1) * 136 + t] = f2bf(v.y);
      sTs[(c0 + 2) * 136 + t] = f2bf(v.z);
      sTs[(c0 + 3) * 136 + t] = f2bf(v.w);
    }
    if (tid < 64) {            // colsum: 4 lanes per column
      int c = tid & 15, qq = tid >> 4;
      float cs = 0.f;
      for (int tt = qq; tt < 128; tt += 4) cs += s[(size_t)g * 2048 + tt * 16 + c];
      cs += __shfl_xor(cs, 16); cs += __shfl_xor(cs, 32);
      if (qq == 0) colsumS[c] = cs;
    }
  }
  __syncthreads();

  // ---- phase 1: edge binning (2048 edges, 4 per thread), swizzled quads ----
  {
    const int e0 = g * EPG;
#pragma unroll
    for (int i = 0; i < 4; ++i) {
      int e = e0 + i * 512 + tid;
      int t = etgt[e] & 127;
      int sl = esrc[e] & 127;
      int dir = (emask[e] != 0) ? 0 : 1;
      atomicAdd(&Mlds[dir * 8192 + t * 64 + (((sl >> 3) ^ (t & 7)) << 2) + ((sl >> 1) & 3)],
                1u << ((sl & 1) * 16));
    }
  }
  __syncthreads();

  // ---- phase 2: in-place count->bf16 (x inv-degree) + fin/fout ----
  {
    const int t = t0 + m;
    const int mm = m & 7;
    unsigned nin = 0, nout = 0;
#pragma unroll
    for (int k4 = 0; k4 < 4; ++k4) {
      int sl = (((q * 4 + k4) ^ mm) & 15) << 2;   // XOR-rotated phys slot order
      uint4 a = *(const uint4*)&Mlds[t * 64 + sl];
      uint4 b = *(const uint4*)&Mlds[8192 + t * 64 + sl];
      nin  += (a.x & 0xffffu) + (a.x >> 16) + (a.y & 0xffffu) + (a.y >> 16)
            + (a.z & 0xffffu) + (a.z >> 16) + (a.w & 0xffffu) + (a.w >> 16);
      nout += (b.x & 0xffffu) + (b.x >> 16) + (b.y & 0xffffu) + (b.y >> 16)
            + (b.z & 0xffffu) + (b.z >> 16) + (b.w & 0xffffu) + (b.w >> 16);
    }
    nin  += __shfl_xor((int)nin, 16);  nin  += __shfl_xor((int)nin, 32);
    nout += __shfl_xor((int)nout, 16); nout += __shfl_xor((int)nout, 32);
    unsigned dg = nin + nout;
    float inv = 1.0f / (float)(dg > 0 ? dg : 1);
    if (q == 0) { finS[t] = (float)nin * inv; foutS[t] = (float)nout * inv; }
#pragma unroll
    for (int d = 0; d < 2; ++d)
#pragma unroll
      for (int k4 = 0; k4 < 4; ++k4) {
        int sl = (((q * 4 + k4) ^ mm) & 15) << 2;
        unsigned* p = &Mlds[d * 8192 + t * 64 + sl];
        uint4 v = *(const uint4*)p;
        uint4 o;
        o.x = bfpack((float)(v.x & 0xffffu) * inv, (float)(v.x >> 16) * inv);
        o.y = bfpack((float)(v.y & 0xffffu) * inv, (float)(v.y >> 16) * inv);
        o.z = bfpack((float)(v.z & 0xffffu) * inv, (float)(v.z >> 16) * inv);
        o.w = bfpack((float)(v.w & 0xffffu) * inv, (float)(v.w >> 16) * inv);
        *(uint4*)p = o;
      }
  }
  __syncthreads();

  // ---- layers ----
  for (int L = 0; L < LLd; ++L) {
    f32x4 pre[8];
#pragma unroll
    for (int ct = 0; ct < 8; ++ct) pre[ct] = (f32x4){0.f, 0.f, 0.f, 0.f};
    f32x4 accT[8];

#pragma unroll
    for (int sg = 0; sg < 2; ++sg) {
      const unsigned short* Wg = (sg == 0 ? Wnb : Wob) + L * 16384;
      // --- M phase: accT[ft] = (Agg^T)[f-tile][t-slice], B-frags from Mlds ---
#pragma unroll
      for (int ft = 0; ft < 8; ++ft) accT[ft] = (f32x4){0.f, 0.f, 0.f, 0.f};
#pragma unroll
      for (int hf = 0; hf < 2; ++hf)
#pragma unroll
        for (int ksl = 0; ksl < 2; ++ksl) {
          const int ksg = hf * 2 + ksl;
          short8 bfr = *(const short8*)&Mlds[sg * 8192 + (t0 + m) * 64 + (((ksg * 4 + q) ^ (m & 7)) << 2)];
#pragma unroll
          for (int ft = 0; ft < 8; ++ft) {
            short8 afr = *(const short8*)&hTs[hchunk(ft * 16 + m, ksg * 4 + q)];
            accT[ft] = __builtin_amdgcn_mfma_f32_16x16x32_bf16(afr, bfr, accT[ft], 0, 0, 0);
          }
        }
      // --- main phase: pre += Agg * W^T ---
      // Transpose: pack bf16(lo)|bf16(hi) BEFORE the shuffle -> one bpermute moves
      // both halves; destination selects by q>>1. Halves the ds_bpermute count.
#pragma unroll
      for (int hf = 0; hf < 2; ++hf)
#pragma unroll
        for (int ksl = 0; ksl < 2; ++ksl) {
          const int ksg = hf * 2 + ksl;
          f32x4 lo = accT[2 * ksg], hi = accT[2 * ksg + 1];
          unsigned pk[4];
#pragma unroll
          for (int r = 0; r < 4; ++r) pk[r] = bfpack(lo[r], hi[r]);
          short8 afr;
#pragma unroll
          for (int j = 0; j < 8; ++j) {
            int srcl = ((((q & 1) << 1) + (j >> 2)) << 4) + m;
            unsigned v = (unsigned)__shfl((int)pk[j & 3], srcl, 64);
            afr[j] = (short)(unsigned short)((q >> 1) ? (v >> 16) : (v & 0xffffu));
          }
#pragma unroll
          for (int ct = 0; ct < 8; ++ct) {
            short8 bfr = *(const short8*)&Wg[(ct * 16 + m) * 128 + ksg * 32 + q * 8];
            pre[ct] = __builtin_amdgcn_mfma_f32_16x16x32_bf16(afr, bfr, pre[ct], 0, 0, 0);
          }
        }
    }
    // --- Wr segment: A-frags scalar-read from hTs, B from global bf16 ---
    {
      const unsigned short* Wrg = Wrb + L * 16384;
#pragma unroll
      for (int hf = 0; hf < 2; ++hf)
#pragma unroll
        for (int ksl = 0; ksl < 2; ++ksl) {
          const int ksg = hf * 2 + ksl;
          short8 afr;
#pragma unroll
          for (int j = 0; j < 8; ++j)
            afr[j] = (short)hTs[hidx(ksg * 32 + q * 8 + j, t0 + m)];
#pragma unroll
          for (int ct = 0; ct < 8; ++ct) {
            short8 bfr = *(const short8*)&Wrg[(ct * 16 + m) * 128 + ksg * 32 + q * 8];
            pre[ct] = __builtin_amdgcn_mfma_f32_16x16x32_bf16(afr, bfr, pre[ct], 0, 0, 0);
          }
        }
    }
    __syncthreads();   // all hTs reads done before overwrite
    // --- epilogue: bias mix + LN + ReLU -> hTs (own wave's t-columns: race-free) ---
    {
      float bnv[8], bov[8], gv[8], bv[8];
#pragma unroll
      for (int ct = 0; ct < 8; ++ct) {
        int c = L * 128 + ct * 16 + m;
        bnv[ct] = bn[c]; bov[ct] = bo[c]; gv[ct] = lng[c]; bv[ct] = lnb[c];
      }
#pragma unroll
      for (int r = 0; r < 4; ++r) {
        const int tl = q * 4 + r;
        const float fiv = finS[t0 + tl], fov = foutS[t0 + tl];
        float v[8];
        float sum = 0.f;
#pragma unroll
        for (int ct = 0; ct < 8; ++ct) {
          v[ct] = pre[ct][r] + fiv * bnv[ct] + fov * bov[ct];
          sum += v[ct];
        }
        sum += __shfl_xor(sum, 1); sum += __shfl_xor(sum, 2);
        sum += __shfl_xor(sum, 4); sum += __shfl_xor(sum, 8);
        const float mu = sum * (1.0f / 128.0f);
        float sq = 0.f;
#pragma unroll
        for (int ct = 0; ct < 8; ++ct) { float d = v[ct] - mu; sq += d * d; }
        sq += __shfl_xor(sq, 1); sq += __shfl_xor(sq, 2);
        sq += __shfl_xor(sq, 4); sq += __shfl_xor(sq, 8);
        const float rstd = rsqrtf(sq * (1.0f / 128.0f) + 1e-5f);
#pragma unroll
        for (int ct = 0; ct < 8; ++ct) {
          float o = fmaxf((v[ct] - mu) * rstd * gv[ct] + bv[ct], 0.0f);
          hTs[hidx(ct * 16 + m, t0 + tl)] = f2bf(o);
        }
      }
    }
    __syncthreads();
  }

  // ---- pool: pooled[c][fo] = sum_t s[t][c]*h[t][fo]; wave w does fo-tile w ----
  f32x4 pl = (f32x4){0.f, 0.f, 0.f, 0.f};
#pragma unroll
  for (int ks = 0; ks < 4; ++ks) {
    short8 a = *(const short8*)&sTs[m * 136 + ks * 32 + q * 8];
    short8 b = *(const short8*)&hTs[hchunk(wave * 16 + m, ks * 4 + q)];
    pl = __builtin_amdgcn_mfma_f32_16x16x32_bf16(a, b, pl, 0, 0, 0);
  }
  float* pooledS = (float*)Mlds;   // M dead since last M-phase (>=2 barriers ago)
#pragma unroll
  for (int r = 0; r < 4; ++r) pooledS[(q * 4 + r) * 132 + wave * 16 + m] = pl[r];
  __syncthreads();

  // ---- final LN + lin + mask (threads 0..255) ----
  if (tid < 256) {
    const int c = tid >> 4;
    const int j0 = (tid & 15) << 3;
    float v[8];
#pragma unroll
    for (int jj = 0; jj < 8; ++jj) v[jj] = pooledS[c * 132 + j0 + jj];
    float sum = 0.f;
#pragma unroll
    for (int jj = 0; jj < 8; ++jj) sum += v[jj];
#pragma unroll
    for (int mk = 1; mk < 16; mk <<= 1) sum += __shfl_xor(sum, mk, 64);
    float mu = sum * (1.0f / 128.0f);
    float sq = 0.f;
#pragma unroll
    for (int jj = 0; jj < 8; ++jj) { float d = v[jj] - mu; sq += d * d; }
#pragma unroll
    for (int mk = 1; mk < 16; mk <<= 1) sq += __shfl_xor(sq, mk, 64);
    float rstd = rsqrtf(sq * (1.0f / 128.0f) + 1e-5f);
    float dot = 0.f;
#pragma unroll
    for (int jj = 0; jj < 8; ++jj) {
      float nv = (v[jj] - mu) * rstd * flng[j0 + jj] + flnb[j0 + jj];
      dot += nv * linw[j0 + jj];
    }
#pragma unroll
    for (int mk = 1; mk < 16; mk <<= 1) dot += __shfl_xor(dot, mk, 64);
    if ((tid & 15) == 0) {
      float cm = (colsumS[c] > 0.f) ? 1.0f : 0.0f;
      float xcv = dot * cm;
      out[257 + g * CCd + c] = xcv;
      xcs[c] = xcv; axcs[c] = fabsf(xcv); msk[c] = cm;
    }
  }
  __syncthreads();
  if (tid == 0) {
    float so = 0.f, sa = 0.f, sd = 0.f;
#pragma unroll
    for (int k = 0; k < CCd; ++k) { so += xcs[k]; sa += axcs[k]; sd += msk[k] + 1e-7f; }
    out[g] = so + bias[0];
    l1g[g] = sa / sd;
  }
}

// ---------------- combine: losses = 0.01*reg + 0.01*mean_g(l1g) ----------------
__global__ __launch_bounds__(256) void combine_kernel(const float* __restrict__ l1g, const float* __restrict__ wsreg,
                                                      float* __restrict__ outp) {
  const int tid = threadIdx.x;
  float s2 = l1g[tid];
#pragma unroll
  for (int mk = 1; mk < 64; mk <<= 1) s2 += __shfl_xor(s2, mk, 64);
  __shared__ float rs2[4];
  if ((tid & 63) == 0) rs2[tid >> 6] = s2;
  __syncthreads();
  if (tid == 0) {
    float l1 = (rs2[0] + rs2[1] + rs2[2] + rs2[3]) * (1.0f / GG);
    outp[0] = 0.01f * wsreg[0] + 0.01f * l1;
  }
}

extern "C" void kernel_launch(void* const* d_in, const int* in_sizes, int n_in,
                              void* d_out, int out_size, void* d_ws, size_t ws_size,
                              hipStream_t stream) {
  (void)in_sizes; (void)n_in; (void)out_size; (void)ws_size;
  const float* x    = (const float*)d_in[0];
  const int*   ei   = (const int*)d_in[1];
  const int*   mask = (const int*)d_in[2];
  const float* s    = (const float*)d_in[3];
  const float* Wn   = (const float*)d_in[5];
  const float* bn   = (const float*)d_in[6];
  const float* Wo   = (const float*)d_in[7];
  const float* bo   = (const float*)d_in[8];
  const float* Wr   = (const float*)d_in[9];
  const float* lng  = (const float*)d_in[10];
  const float* lnb  = (const float*)d_in[11];
  const float* flng = (const float*)d_in[12];
  const float* flnb = (const float*)d_in[13];
  const float* linw = (const float*)d_in[14];
  const float* bias = (const float*)d_in[15];
  float* out = (float*)d_out;

  char* ws = (char*)d_ws;
  size_t off = 0;
  auto alloc = [&](size_t b) { char* p = ws + off; off += (b + 255) & ~(size_t)255; return p; };
  unsigned short* Wnb = (unsigned short*)alloc((size_t)LLd * HD * HD * 2);
  unsigned short* Wob = (unsigned short*)alloc((size_t)LLd * HD * HD * 2);
  unsigned short* Wrb = (unsigned short*)alloc((size_t)LLd * HD * HD * 2);
  float* l1g    = (float*)alloc((size_t)GG * 4);
  float* wsreg  = (float*)alloc(256);

  const int* srcA = ei;
  const int* tgtA = ei + EE;

  hipMemsetAsync(wsreg, 0, 4, stream);
  convert_w_kernel<<<LLd * HD * HD / (256 * 4), 256, 0, stream>>>(Wn, Wo, Wr, bo,
      (unsigned*)Wnb, (unsigned*)Wob, (unsigned*)Wrb, wsreg);
  fused_kernel<<<GG, 512, 0, stream>>>(x, srcA, tgtA, mask, Wnb, Wob, Wrb, bn, bo,
                                       lng, lnb, s, flng, flnb, linw, bias, out, l1g);
  combine_kernel<<<1, 256, 0, stream>>>(l1g, wsreg, out + 256);
}

// Round 5
// 142.107 us; speedup vs baseline: 1.8683x; 1.8683x over previous
//
#include <hip/hip_runtime.h>

#define NN   32768
#define HD   128
#define EE   524288
#define GG   256
#define EPG  2048
#define CCd  16
#define LLd  3

typedef short short8 __attribute__((ext_vector_type(8)));   // 8 bf16 = 4 VGPRs
typedef float f32x4 __attribute__((ext_vector_type(4)));

__device__ __forceinline__ unsigned short f2bf(float f) {
  unsigned u = __builtin_bit_cast(unsigned, f);
  return (unsigned short)((u + 0x7FFFu + ((u >> 16) & 1u)) >> 16);  // RNE
}
__device__ __forceinline__ unsigned bfpack(float a, float b) {
  return (unsigned)f2bf(a) | ((unsigned)f2bf(b) << 16);
}

// hTs layout: [f][t] bf16, stride 128 (no pad), 16-B chunks XOR-swizzled:
//   phys = (c&8) | ((c ^ f ^ (f>>3)) & 7),  c = t>>3
// Spreads both row-major b128 reads and column scalar writes across bank groups.
__device__ __forceinline__ int hchunk(int f, int c) {
  return f * 128 + (((c & 8) | ((c ^ f ^ (f >> 3)) & 7)) << 3);
}
__device__ __forceinline__ int hidx(int f, int t) {
  return hchunk(f, t >> 3) + (t & 7);
}

// ---------------- convert weights to bf16 + reg_loss accumulate ----------------
__global__ __launch_bounds__(256) void convert_w_kernel(const float* __restrict__ Wn, const float* __restrict__ Wo,
                                                        const float* __restrict__ Wr, const float* __restrict__ bo,
                                                        unsigned* __restrict__ Wnb, unsigned* __restrict__ Wob,
                                                        unsigned* __restrict__ Wrb, float* __restrict__ wsreg) {
  int i = blockIdx.x * 256 + threadIdx.x;   // 48 blocks; 4 floats per array per thread
  float4 a = *(const float4*)(Wn + (size_t)i * 4);
  float4 b = *(const float4*)(Wo + (size_t)i * 4);
  float4 c = *(const float4*)(Wr + (size_t)i * 4);
  *(uint2*)(Wnb + (size_t)i * 2) = make_uint2(bfpack(a.x, a.y), bfpack(a.z, a.w));
  *(uint2*)(Wob + (size_t)i * 2) = make_uint2(bfpack(b.x, b.y), bfpack(b.z, b.w));
  *(uint2*)(Wrb + (size_t)i * 2) = make_uint2(bfpack(c.x, c.y), bfpack(c.z, c.w));
  float s = fabsf(b.x) + fabsf(b.y) + fabsf(b.z) + fabsf(b.w);
  if (blockIdx.x == 0 && threadIdx.x < 96) {       // 384 bo elements
    float4 d = *(const float4*)(bo + threadIdx.x * 4);
    s += fabsf(d.x) + fabsf(d.y) + fabsf(d.z) + fabsf(d.w);
  }
#pragma unroll
  for (int mk = 1; mk < 64; mk <<= 1) s += __shfl_xor(s, mk, 64);
  if ((threadIdx.x & 63) == 0) atomicAdd(wsreg, s);
}

// ---------------- fully fused per-graph network ----------------
// grid 256 (1 block/graph), 512 threads (8 waves; wave w owns node rows [16w,16w+16)).
// Round-2 structure (proven 53us): W via rotating 32KB LDS buffer with 16-VGPR
// register prefetch (NEVER global-direct MFMA operands -> spills, r1/r4).
// + hchunk hTs swizzle, phase-2 XOR rotation, packed single-shfl transpose.
__global__ __launch_bounds__(512, 2) void fused_kernel(
    const float* __restrict__ x,
    const int* __restrict__ esrc, const int* __restrict__ etgt, const int* __restrict__ emask,
    const unsigned short* __restrict__ Wnb, const unsigned short* __restrict__ Wob,
    const unsigned short* __restrict__ Wrb,
    const float* __restrict__ bn, const float* __restrict__ bo,
    const float* __restrict__ lng, const float* __restrict__ lnb,
    const float* __restrict__ s,
    const float* __restrict__ flng, const float* __restrict__ flnb,
    const float* __restrict__ linw, const float* __restrict__ bias,
    float* __restrict__ out, float* __restrict__ l1g) {
  __shared__ __align__(16) unsigned short hTs[128 * 128];  // 32.0 KB  h^T, XOR-swizzled
  __shared__ __align__(16) unsigned short sTs[16 * 136];   //  4.3 KB  s^T [c][t]
  __shared__ __align__(16) unsigned Mlds[2 * 128 * 64];    // 64.0 KB  counts -> bf16 M; pool scratch later
  __shared__ __align__(16) unsigned Wlds[128 * 64];        // 32.0 KB  rotating W (bf16, swizzled)
  __shared__ float finS[128], foutS[128];
  __shared__ float colsumS[CCd], xcs[CCd], axcs[CCd], msk[CCd];

  const int g = blockIdx.x;
  const int tid = threadIdx.x;
  const int wave = tid >> 6;
  const int lane = tid & 63;
  const int m = lane & 15;
  const int q = lane >> 4;
  const int t0 = wave << 4;

  // ---- W prefetch registers; issue Wn[0] immediately (hides under phases 0-2) ----
  const int wr = tid >> 2, wq = tid & 3, wsw = wr & 7;
  const int wbase = wr * 16 + wq * 4;
  uint4 wv0, wv1, wv2, wv3;
  {
    const uint4* wp = (const uint4*)Wnb;
    wv0 = wp[wbase + 0]; wv1 = wp[wbase + 1]; wv2 = wp[wbase + 2]; wv3 = wp[wbase + 3];
  }
  auto w_store = [&]() {
    *(uint4*)&Wlds[wr * 64 + (((wq * 4 + 0) ^ wsw) << 2)] = wv0;
    *(uint4*)&Wlds[wr * 64 + (((wq * 4 + 1) ^ wsw) << 2)] = wv1;
    *(uint4*)&Wlds[wr * 64 + (((wq * 4 + 2) ^ wsw) << 2)] = wv2;
    *(uint4*)&Wlds[wr * 64 + (((wq * 4 + 3) ^ wsw) << 2)] = wv3;
  };
  auto w_load = [&](const unsigned short* Wg) {
    const uint4* wp = (const uint4*)Wg;
    wv0 = wp[wbase + 0]; wv1 = wp[wbase + 1]; wv2 = wp[wbase + 2]; wv3 = wp[wbase + 3];
  };

  // ---- phase 0: zero Mlds + stage x->hTs (swizzled), s->sTs, colsum ----
  {
    uint4* cz = (uint4*)Mlds;   // 4096 uint4
#pragma unroll
    for (int i = 0; i < 8; ++i) cz[i * 512 + tid] = make_uint4(0u, 0u, 0u, 0u);

    const float4* xg = (const float4*)(x + (size_t)g * 16384);
#pragma unroll
    for (int i = 0; i < 8; ++i) {
      int flat = i * 512 + tid;           // 4096 float4s, fully coalesced
      int t = flat >> 5, f0 = (flat & 31) << 2;
      float4 v = xg[flat];
      hTs[hidx(f0 + 0, t)] = f2bf(v.x);
      hTs[hidx(f0 + 1, t)] = f2bf(v.y);
      hTs[hidx(f0 + 2, t)] = f2bf(v.z);
      hTs[hidx(f0 + 3, t)] = f2bf(v.w);
    }
    {
      int t = tid >> 2, c0 = (tid & 3) << 2;
      float4 v = *(const float4*)(s + (size_t)g * 2048 + t * 16 + c0);
      sTs[(c0 + 0) * 136 + t] = f2bf(v.x);
      sTs[(c0 + 1) * 136 + t] = f2bf(v.y);
      sTs[(c0 + 2) * 136 + t] = f2bf(v.z);
      sTs[(c0 + 3) * 136 + t] = f2bf(v.w);
    }
    if (tid < 64) {            // colsum: 4 lanes per column
      int c = tid & 15, qq = tid >> 4;
      float cs = 0.f;
      for (int tt = qq; tt < 128; tt += 4) cs += s[(size_t)g * 2048 + tt * 16 + c];
      cs += __shfl_xor(cs, 16); cs += __shfl_xor(cs, 32);
      if (qq == 0) colsumS[c] = cs;
    }
  }
  __syncthreads();

  // ---- phase 1: edge binning (2048 edges, 4 per thread), swizzled quads ----
  {
    const int e0 = g * EPG;
#pragma unroll
    for (int i = 0; i < 4; ++i) {
      int e = e0 + i * 512 + tid;
      int t = etgt[e] & 127;
      int sl = esrc[e] & 127;
      int dir = (emask[e] != 0) ? 0 : 1;
      atomicAdd(&Mlds[dir * 8192 + t * 64 + (((sl >> 3) ^ (t & 7)) << 2) + ((sl >> 1) & 3)],
                1u << ((sl & 1) * 16));
    }
  }
  __syncthreads();

  // ---- phase 2: in-place count->bf16 (x inv-degree) + fin/fout (XOR slot order) ----
  {
    const int t = t0 + m;
    const int mm = m & 7;
    unsigned nin = 0, nout = 0;
#pragma unroll
    for (int k4 = 0; k4 < 4; ++k4) {
      int sl = (((q * 4 + k4) ^ mm) & 15) << 2;   // XOR-rotated phys slot order
      uint4 a = *(const uint4*)&Mlds[t * 64 + sl];
      uint4 b = *(const uint4*)&Mlds[8192 + t * 64 + sl];
      nin  += (a.x & 0xffffu) + (a.x >> 16) + (a.y & 0xffffu) + (a.y >> 16)
            + (a.z & 0xffffu) + (a.z >> 16) + (a.w & 0xffffu) + (a.w >> 16);
      nout += (b.x & 0xffffu) + (b.x >> 16) + (b.y & 0xffffu) + (b.y >> 16)
            + (b.z & 0xffffu) + (b.z >> 16) + (b.w & 0xffffu) + (b.w >> 16);
    }
    nin  += __shfl_xor((int)nin, 16);  nin  += __shfl_xor((int)nin, 32);
    nout += __shfl_xor((int)nout, 16); nout += __shfl_xor((int)nout, 32);
    unsigned dg = nin + nout;
    float inv = 1.0f / (float)(dg > 0 ? dg : 1);
    if (q == 0) { finS[t] = (float)nin * inv; foutS[t] = (float)nout * inv; }
#pragma unroll
    for (int d = 0; d < 2; ++d)
#pragma unroll
      for (int k4 = 0; k4 < 4; ++k4) {
        int sl = (((q * 4 + k4) ^ mm) & 15) << 2;
        unsigned* p = &Mlds[d * 8192 + t * 64 + sl];
        uint4 v = *(const uint4*)p;
        uint4 o;
        o.x = bfpack((float)(v.x & 0xffffu) * inv, (float)(v.x >> 16) * inv);
        o.y = bfpack((float)(v.y & 0xffffu) * inv, (float)(v.y >> 16) * inv);
        o.z = bfpack((float)(v.z & 0xffffu) * inv, (float)(v.z >> 16) * inv);
        o.w = bfpack((float)(v.w & 0xffffu) * inv, (float)(v.w >> 16) * inv);
        *(uint4*)p = o;
      }
  }
  __syncthreads();

  // ---- layers ----
  for (int L = 0; L < LLd; ++L) {
    f32x4 pre[8];
#pragma unroll
    for (int ct = 0; ct < 8; ++ct) pre[ct] = (f32x4){0.f, 0.f, 0.f, 0.f};
    f32x4 accT[8];

#pragma unroll
    for (int sg = 0; sg < 2; ++sg) {
      // --- M phase: accT[ft] = (Agg^T)[f-tile][t-slice], B-frags from Mlds ---
#pragma unroll
      for (int ft = 0; ft < 8; ++ft) accT[ft] = (f32x4){0.f, 0.f, 0.f, 0.f};
#pragma unroll
      for (int hf = 0; hf < 2; ++hf)
#pragma unroll
        for (int ksl = 0; ksl < 2; ++ksl) {
          const int ksg = hf * 2 + ksl;
          short8 bfr = *(const short8*)&Mlds[sg * 8192 + (t0 + m) * 64 + (((ksg * 4 + q) ^ (m & 7)) << 2)];
#pragma unroll
          for (int ft = 0; ft < 8; ++ft) {
            short8 afr = *(const short8*)&hTs[hchunk(ft * 16 + m, ksg * 4 + q)];
            accT[ft] = __builtin_amdgcn_mfma_f32_16x16x32_bf16(afr, bfr, accT[ft], 0, 0, 0);
          }
        }
      // rotate W: store current (Wn/Wo), prefetch next (Wo/Wr)
      __syncthreads();   // prior Wlds readers done
      w_store();
      w_load((sg == 0 ? Wob : Wrb) + L * 16384);
      __syncthreads();   // Wlds ready
      // --- main phase: pre += Agg * W^T ---
      // Packed transpose: bf16(lo)|bf16(hi)<<16 BEFORE the shuffle; one bpermute
      // moves both halves; destination selects by q>>1.
#pragma unroll
      for (int hf = 0; hf < 2; ++hf)
#pragma unroll
        for (int ksl = 0; ksl < 2; ++ksl) {
          const int ksg = hf * 2 + ksl;
          f32x4 lo = accT[2 * ksg], hi = accT[2 * ksg + 1];
          unsigned pk[4];
#pragma unroll
          for (int r = 0; r < 4; ++r) pk[r] = bfpack(lo[r], hi[r]);
          short8 afr;
#pragma unroll
          for (int j = 0; j < 8; ++j) {
            int srcl = ((((q & 1) << 1) + (j >> 2)) << 4) + m;
            unsigned v = (unsigned)__shfl((int)pk[j & 3], srcl, 64);
            afr[j] = (short)(unsigned short)((q >> 1) ? (v >> 16) : (v & 0xffffu));
          }
#pragma unroll
          for (int ct = 0; ct < 8; ++ct) {
            short8 bfr = *(const short8*)&Wlds[(ct * 16 + m) * 64 + (((ksg * 4 + q) ^ (m & 7)) << 2)];
            pre[ct] = __builtin_amdgcn_mfma_f32_16x16x32_bf16(afr, bfr, pre[ct], 0, 0, 0);
          }
        }
    }
    // rotate W: store Wr[L], prefetch Wn[L+1] (if any)
    __syncthreads();
    w_store();
    if (L < LLd - 1) w_load(Wnb + (L + 1) * 16384);
    __syncthreads();
    // --- Wr segment: A-frags scalar-read from hTs, B from Wlds ---
#pragma unroll
    for (int hf = 0; hf < 2; ++hf)
#pragma unroll
      for (int ksl = 0; ksl < 2; ++ksl) {
        const int ksg = hf * 2 + ksl;
        short8 afr;
#pragma unroll
        for (int j = 0; j < 8; ++j)
          afr[j] = (short)hTs[hidx(ksg * 32 + q * 8 + j, t0 + m)];
#pragma unroll
        for (int ct = 0; ct < 8; ++ct) {
          short8 bfr = *(const short8*)&Wlds[(ct * 16 + m) * 64 + (((ksg * 4 + q) ^ (m & 7)) << 2)];
          pre[ct] = __builtin_amdgcn_mfma_f32_16x16x32_bf16(afr, bfr, pre[ct], 0, 0, 0);
        }
      }
    __syncthreads();   // all hTs reads done before overwrite
    // --- epilogue: bias mix + LN + ReLU -> hTs (own wave's t-columns: race-free) ---
    {
      float bnv[8], bov[8], gv[8], bv[8];
#pragma unroll
      for (int ct = 0; ct < 8; ++ct) {
        int c = L * 128 + ct * 16 + m;
        bnv[ct] = bn[c]; bov[ct] = bo[c]; gv[ct] = lng[c]; bv[ct] = lnb[c];
      }
#pragma unroll
      for (int r = 0; r < 4; ++r) {
        const int tl = q * 4 + r;
        const float fiv = finS[t0 + tl], fov = foutS[t0 + tl];
        float v[8];
        float sum = 0.f;
#pragma unroll
        for (int ct = 0; ct < 8; ++ct) {
          v[ct] = pre[ct][r] + fiv * bnv[ct] + fov * bov[ct];
          sum += v[ct];
        }
        sum += __shfl_xor(sum, 1); sum += __shfl_xor(sum, 2);
        sum += __shfl_xor(sum, 4); sum += __shfl_xor(sum, 8);
        const float mu = sum * (1.0f / 128.0f);
        float sq = 0.f;
#pragma unroll
        for (int ct = 0; ct < 8; ++ct) { float d = v[ct] - mu; sq += d * d; }
        sq += __shfl_xor(sq, 1); sq += __shfl_xor(sq, 2);
        sq += __shfl_xor(sq, 4); sq += __shfl_xor(sq, 8);
        const float rstd = rsqrtf(sq * (1.0f / 128.0f) + 1e-5f);
#pragma unroll
        for (int ct = 0; ct < 8; ++ct) {
          float o = fmaxf((v[ct] - mu) * rstd * gv[ct] + bv[ct], 0.0f);
          hTs[hidx(ct * 16 + m, t0 + tl)] = f2bf(o);
        }
      }
    }
    __syncthreads();
  }

  // ---- pool: pooled[c][fo] = sum_t s[t][c]*h[t][fo]; wave w does fo-tile w ----
  f32x4 pl = (f32x4){0.f, 0.f, 0.f, 0.f};
#pragma unroll
  for (int ks = 0; ks < 4; ++ks) {
    short8 a = *(const short8*)&sTs[m * 136 + ks * 32 + q * 8];
    short8 b = *(const short8*)&hTs[hchunk(wave * 16 + m, ks * 4 + q)];
    pl = __builtin_amdgcn_mfma_f32_16x16x32_bf16(a, b, pl, 0, 0, 0);
  }
  float* pooledS = (float*)Mlds;   // M dead since last M-phase (>=2 barriers ago)
#pragma unroll
  for (int r = 0; r < 4; ++r) pooledS[(q * 4 + r) * 132 + wave * 16 + m] = pl[r];
  __syncthreads();

  // ---- final LN + lin + mask (threads 0..255) ----
  if (tid < 256) {
    const int c = tid >> 4;
    const int j0 = (tid & 15) << 3;
    float v[8];
#pragma unroll
    for (int jj = 0; jj < 8; ++jj) v[jj] = pooledS[c * 132 + j0 + jj];
    float sum = 0.f;
#pragma unroll
    for (int jj = 0; jj < 8; ++jj) sum += v[jj];
#pragma unroll
    for (int mk = 1; mk < 16; mk <<= 1) sum += __shfl_xor(sum, mk, 64);
    float mu = sum * (1.0f / 128.0f);
    float sq = 0.f;
#pragma unroll
    for (int jj = 0; jj < 8; ++jj) { float d = v[jj] - mu; sq += d * d; }
#pragma unroll
    for (int mk = 1; mk < 16; mk <<= 1) sq += __shfl_xor(sq, mk, 64);
    float rstd = rsqrtf(sq * (1.0f / 128.0f) + 1e-5f);
    float dot = 0.f;
#pragma unroll
    for (int jj = 0; jj < 8; ++jj) {
      float nv = (v[jj] - mu) * rstd * flng[j0 + jj] + flnb[j0 + jj];
      dot += nv * linw[j0 + jj];
    }
#pragma unroll
    for (int mk = 1; mk < 16; mk <<= 1) dot += __shfl_xor(dot, mk, 64);
    if ((tid & 15) == 0) {
      float cm = (colsumS[c] > 0.f) ? 1.0f : 0.0f;
      float xcv = dot * cm;
      out[257 + g * CCd + c] = xcv;
      xcs[c] = xcv; axcs[c] = fabsf(xcv); msk[c] = cm;
    }
  }
  __syncthreads();
  if (tid == 0) {
    float so = 0.f, sa = 0.f, sd = 0.f;
#pragma unroll
    for (int k = 0; k < CCd; ++k) { so += xcs[k]; sa += axcs[k]; sd += msk[k] + 1e-7f; }
    out[g] = so + bias[0];
    l1g[g] = sa / sd;
  }
}

// ---------------- combine: losses = 0.01*reg + 0.01*mean_g(l1g) ----------------
__global__ __launch_bounds__(256) void combine_kernel(const float* __restrict__ l1g, const float* __restrict__ wsreg,
                                                      float* __restrict__ outp) {
  const int tid = threadIdx.x;
  float s2 = l1g[tid];
#pragma unroll
  for (int mk = 1; mk < 64; mk <<= 1) s2 += __shfl_xor(s2, mk, 64);
  __shared__ float rs2[4];
  if ((tid & 63) == 0) rs2[tid >> 6] = s2;
  __syncthreads();
  if (tid == 0) {
    float l1 = (rs2[0] + rs2[1] + rs2[2] + rs2[3]) * (1.0f / GG);
    outp[0] = 0.01f * wsreg[0] + 0.01f * l1;
  }
}

extern "C" void kernel_launch(void* const* d_in, const int* in_sizes, int n_in,
                              void* d_out, int out_size, void* d_ws, size_t ws_size,
                              hipStream_t stream) {
  (void)in_sizes; (void)n_in; (void)out_size; (void)ws_size;
  const float* x    = (const float*)d_in[0];
  const int*   ei   = (const int*)d_in[1];
  const int*   mask = (const int*)d_in[2];
  const float* s    = (const float*)d_in[3];
  const float* Wn   = (const float*)d_in[5];
  const float* bn   = (const float*)d_in[6];
  const float* Wo   = (const float*)d_in[7];
  const float* bo   = (const float*)d_in[8];
  const float* Wr   = (const float*)d_in[9];
  const float* lng  = (const float*)d_in[10];
  const float* lnb  = (const float*)d_in[11];
  const float* flng = (const float*)d_in[12];
  const float* flnb = (const float*)d_in[13];
  const float* linw = (const float*)d_in[14];
  const float* bias = (const float*)d_in[15];
  float* out = (float*)d_out;

  char* ws = (char*)d_ws;
  size_t off = 0;
  auto alloc = [&](size_t b) { char* p = ws + off; off += (b + 255) & ~(size_t)255; return p; };
  unsigned short* Wnb = (unsigned short*)alloc((size_t)LLd * HD * HD * 2);
  unsigned short* Wob = (unsigned short*)alloc((size_t)LLd * HD * HD * 2);
  unsigned short* Wrb = (unsigned short*)alloc((size_t)LLd * HD * HD * 2);
  float* l1g    = (float*)alloc((size_t)GG * 4);
  float* wsreg  = (float*)alloc(256);

  const int* srcA = ei;
  const int* tgtA = ei + EE;

  hipMemsetAsync(wsreg, 0, 4, stream);
  convert_w_kernel<<<LLd * HD * HD / (256 * 4), 256, 0, stream>>>(Wn, Wo, Wr, bo,
      (unsigned*)Wnb, (unsigned*)Wob, (unsigned*)Wrb, wsreg);
  fused_kernel<<<GG, 512, 0, stream>>>(x, srcA, tgtA, mask, Wnb, Wob, Wrb, bn, bo,
                                       lng, lnb, s, flng, flnb, linw, bias, out, l1g);
  combine_kernel<<<1, 256, 0, stream>>>(l1g, wsreg, out + 256);
}